// Round 3
// baseline (494.729 us; speedup 1.0000x reference)
//
#include <hip/hip_runtime.h>
#include <hip/hip_bf16.h>

// Problem constants (T=2048, B=8, C=512, O=512, RD=64, NE=8, tau=1, commit=0.1)
// All inputs/outputs float32. MoE GEMM: bf16 MFMA on ws copies, m97-style
// global_load_lds staging. GMM assignment + loss: f32 with transposed map_w.
#define NROWS 16384
#define CC 512
#define OO 512
#define RDIM 64
#define NE 8
#define NEXP 9            // 8 experts + bias_w as expert 8 (scale 1.0)
#define COMMIT_SCALE 0.1f
#define LOG2PI_TERM 58.81206612509905f   // (RD/2)*log(2*pi*tau), tau=1

typedef __attribute__((ext_vector_type(8))) short short8;
typedef __attribute__((ext_vector_type(4))) float f32x4;

__device__ __forceinline__ unsigned short f2bf(float f) {
  unsigned int u = __float_as_uint(f);
  u += 0x7fffu + ((u >> 16) & 1u);   // round-to-nearest-even
  return (unsigned short)(u >> 16);
}

__device__ __forceinline__ void gl_lds16(const unsigned short* g, unsigned short* l) {
  __builtin_amdgcn_global_load_lds(
      (const __attribute__((address_space(1))) void*)g,
      (__attribute__((address_space(3))) void*)l, 16, 0, 0);
}

// ---------------------------------------------------------------------------
// Kernel 0: f32->bf16 copies of x and [pw_w ; bias_w]; transpose map_w into
// wT4[c/4][64][4] layout (lane j reads float4 of 4 consecutive c for dim j).
// ---------------------------------------------------------------------------
#define X4 2097152u   // x float4 count      (8388608 / 4)
#define P4 524288u    // pw_w float4 count   (2097152 / 4)
#define B4 65536u     // bias_w float4 count (262144 / 4)
#define NB4 ((X4 + P4 + B4) / 256u)   // 10496 blocks for the convert part
#define TB 128u                        // 32768 map_w elems / 256

__global__ __launch_bounds__(256) void k_prep(
    const float* __restrict__ x, const float* __restrict__ pw,
    const float* __restrict__ bw, const float* __restrict__ mw,
    unsigned short* __restrict__ xb, unsigned short* __restrict__ wb,
    float* __restrict__ wT4)
{
  unsigned int b = blockIdx.x;
  if (b >= NB4) {   // map_w transpose: i indexes map_w[j*512+c]
    unsigned int i = (b - NB4) * 256 + threadIdx.x;
    unsigned int j = i >> 9, c = i & 511u;
    wT4[((c >> 2) << 8) + (j << 2) + (c & 3u)] = mw[i];
    return;
  }
  unsigned int i = b * 256 + threadIdx.x;   // float4 index
  const float* src;
  unsigned short* dst;
  if (i < X4)            { src = x  + (size_t)i * 4;            dst = xb + (size_t)i * 4; }
  else if (i < X4 + P4)  { size_t j = i - X4;  src = pw + j * 4; dst = wb + j * 4; }
  else                   { size_t j = i - X4 - P4; src = bw + j * 4; dst = wb + (size_t)P4 * 4 + j * 4; }
  float4 v = *(const float4*)src;
  ushort4 o;
  o.x = f2bf(v.x); o.y = f2bf(v.y); o.z = f2bf(v.z); o.w = f2bf(v.w);
  *(ushort4*)dst = o;
}

// ---------------------------------------------------------------------------
// Kernel 1: GMM responsibilities + loss (pure f32).
// One wave = 4 rows; lane j owns k_j. map_w read coalesced via wT4.
// ---------------------------------------------------------------------------
__global__ __launch_bounds__(256) void k_assign(
    const float* __restrict__ x,      // [N, C]
    const float* __restrict__ wT4,    // [C/4, 64, 4] transposed map_w
    const float* __restrict__ map_b,  // [RD]
    const float* __restrict__ cent,   // [NE, RD]
    const float* __restrict__ prior,  // [NE]
    float* __restrict__ resp_out,     // [N, NE] f32 (ws)
    float* __restrict__ loss_acc)     // [1] f32 (ws)
{
  __shared__ float lsum[4];
  const int tid  = threadIdx.x;
  const int wid  = tid >> 6;
  const int lane = tid & 63;
  const int row0 = blockIdx.x * 16 + wid * 4;

  const float* xr0 = x + (size_t)row0 * CC;
  float acc[4] = {0.f, 0.f, 0.f, 0.f};
  #pragma unroll 4
  for (int c0 = 0; c0 < CC; c0 += 4) {
    float4 wv = *(const float4*)&wT4[(c0 << 6) + (lane << 2)];  // coalesced
    #pragma unroll
    for (int r = 0; r < 4; ++r) {
      float4 xv = *(const float4*)(xr0 + r * CC + c0);          // wave-uniform
      acc[r] += xv.x * wv.x + xv.y * wv.y + xv.z * wv.z + xv.w * wv.w;
    }
  }
  const float mb = map_b[lane];
  float kk[4] = {acc[0] + mb, acc[1] + mb, acc[2] + mb, acc[3] + mb};

  // centroid column (lane j holds cent[e][j]), |c_e|^2, log prior
  float ce[8], c2[8], lp[8];
  #pragma unroll
  for (int e = 0; e < 8; ++e) {
    ce[e] = cent[e * RDIM + lane];
    float v = ce[e] * ce[e];
    #pragma unroll
    for (int off = 32; off; off >>= 1) v += __shfl_xor(v, off, 64);
    c2[e] = v;
    lp[e] = __logf(prior[e]);
  }

  float dsum = 0.f;
  #pragma unroll
  for (int r = 0; r < 4; ++r) {
    float k = kk[r];
    float v[9];
    v[0] = k * k;
    #pragma unroll
    for (int e = 0; e < 8; ++e) v[e + 1] = k * ce[e];
    #pragma unroll
    for (int off = 32; off; off >>= 1) {
      #pragma unroll
      for (int q = 0; q < 9; ++q) v[q] += __shfl_xor(v[q], off, 64);
    }
    float lr[8], mx = -3.4e38f;
    #pragma unroll
    for (int e = 0; e < 8; ++e) {
      float d2 = v[0] + c2[e] - 2.f * v[e + 1];
      lr[e] = -0.5f * d2 - LOG2PI_TERM + lp[e];
      mx = fmaxf(mx, lr[e]);
    }
    float s = 0.f;
    #pragma unroll
    for (int e = 0; e < 8; ++e) s += __expf(lr[e] - mx);
    float denom = mx + __logf(s);
    dsum += denom;
    float myv = 0.f;
    #pragma unroll
    for (int e = 0; e < 8; ++e) {
      float re = __expf(lr[e] - denom);
      myv = (lane == e) ? re : myv;
    }
    if (lane < 8) resp_out[(size_t)(row0 + r) * NE + lane] = myv;
  }
  if (lane == 0) lsum[wid] = dsum;
  __syncthreads();
  if (tid == 0) {
    float t = lsum[0] + lsum[1] + lsum[2] + lsum[3];
    atomicAdd(loss_acc, -COMMIT_SCALE * t);
  }
}

// ---------------------------------------------------------------------------
// Kernel 2: y = sum_e resp[:,e] * (x @ W_e^T)  (+ bias expert) + bias_b.
// m97-style: 128x128 tile, BK=32, global_load_lds width-16 staging into
// UNPADDED 128x32 LDS tiles with XOR chunk swizzle; 4 waves x 4x4 frags of
// 16x16x32 bf16; expert-outer dual accumulator.
// ---------------------------------------------------------------------------
__global__ __launch_bounds__(256, 2) void k_moe(
    const unsigned short* __restrict__ xb,   // [N, C] bf16 (ws)
    const unsigned short* __restrict__ wb,   // [9, O, C] bf16 (ws)
    const float* __restrict__ bb,            // [O] f32
    const float* __restrict__ resp,          // [N, NE] f32 (ws)
    const float* __restrict__ loss_acc,      // [1] f32 (ws)
    float* __restrict__ out)                 // [N*O + 1] f32
{
  __shared__ unsigned short aT[128 * 32];    // unpadded, row stride 32 shorts
  __shared__ unsigned short bT[128 * 32];
  __shared__ float sc[NEXP * 128];

  const int tid = threadIdx.x;
  const int m0 = blockIdx.x * 128;
  const int o0 = blockIdx.y * 128;

  // stage resp scales: sc[e][row]; expert 8 (bias) = 1.0
  for (int idx = tid; idx < 128 * NE; idx += 256) {
    int r = idx >> 3, e = idx & 7;
    sc[e * 128 + r] = resp[(size_t)(m0 + r) * NE + e];
  }
  if (tid < 128) sc[8 * 128 + tid] = 1.0f;

  const int lane = tid & 63;
  const int wid = tid >> 6;
  const int wm = (wid & 1) * 64;
  const int wn = (wid >> 1) * 64;
  const int fr = lane & 15;      // A: m within tile / B: n within tile
  const int fq = lane >> 4;      // k chunk (*8 shorts), C/D row chunk (*4)

  // global_load_lds staging geometry: each wave covers 32 rows in 2 loads of
  // 16 rows; lane l -> row (l>>2), fetches global chunk (l&3)^((l>>2)&3) so
  // LDS[row][chunk c] holds global chunk c^(row&3) (XOR bank swizzle).
  const int srow = lane >> 2;                         // 0..15 within load
  const int gchunk = (lane & 3) ^ (srow & 3);
  const size_t a_go = (size_t)(m0 + wid * 32 + srow) * CC + gchunk * 8;
  const size_t b_go = (size_t)(o0 + wid * 32 + srow) * CC + gchunk * 8;
  unsigned short* a_l0 = aT + wid * 1024;             // wid*32 rows * 32 shorts
  unsigned short* a_l1 = a_l0 + 512;                  // +16 rows
  unsigned short* b_l0 = bT + wid * 1024;
  unsigned short* b_l1 = b_l0 + 512;
  const size_t row16 = (size_t)16 * CC;

  // fragment read addresses (swizzled chunk = fq ^ (row&3) = fq ^ (fr&3))
  const int rchunk = (fq ^ (fr & 3)) * 8;

  f32x4 zero4 = {0.f, 0.f, 0.f, 0.f};
  f32x4 tot[4][4];
  #pragma unroll
  for (int i = 0; i < 4; ++i)
    #pragma unroll
    for (int j = 0; j < 4; ++j) tot[i][j] = zero4;

  for (int e = 0; e < NEXP; ++e) {
    const unsigned short* Ab = xb + a_go;
    const unsigned short* Bb = wb + (size_t)e * OO * CC + b_go;

    f32x4 ae[4][4];
    #pragma unroll
    for (int i = 0; i < 4; ++i)
      #pragma unroll
      for (int j = 0; j < 4; ++j) ae[i][j] = zero4;

    for (int k0 = 0; k0 < CC; k0 += 32) {
      __syncthreads();   // readers of previous tile done
      gl_lds16(Ab + k0,         a_l0);
      gl_lds16(Ab + k0 + row16, a_l1);
      gl_lds16(Bb + k0,         b_l0);
      gl_lds16(Bb + k0 + row16, b_l1);
      __syncthreads();   // compiler emits vmcnt(0) drain before barrier

      short8 af[4], bfr[4];
      #pragma unroll
      for (int i = 0; i < 4; ++i)
        af[i] = *(const short8*)&aT[(wm + i * 16 + fr) * 32 + rchunk];
      #pragma unroll
      for (int j = 0; j < 4; ++j)
        bfr[j] = *(const short8*)&bT[(wn + j * 16 + fr) * 32 + rchunk];

      #pragma unroll
      for (int i = 0; i < 4; ++i)
        #pragma unroll
        for (int j = 0; j < 4; ++j)
          ae[i][j] = __builtin_amdgcn_mfma_f32_16x16x32_bf16(af[i], bfr[j], ae[i][j], 0, 0, 0);
    }

    // tot += resp[row, e] * ae   (row = wm + i*16 + fq*4 + r)
    #pragma unroll
    for (int i = 0; i < 4; ++i) {
      float s[4];
      #pragma unroll
      for (int r = 0; r < 4; ++r) s[r] = sc[e * 128 + wm + i * 16 + fq * 4 + r];
      #pragma unroll
      for (int j = 0; j < 4; ++j)
        #pragma unroll
        for (int r = 0; r < 4; ++r) tot[i][j][r] += s[r] * ae[i][j][r];
    }
  }

  // epilogue: + bias_b, store f32
  #pragma unroll
  for (int j = 0; j < 4; ++j) {
    const int o = o0 + wn + j * 16 + fr;
    const float bias = bb[o];
    #pragma unroll
    for (int i = 0; i < 4; ++i) {
      #pragma unroll
      for (int r = 0; r < 4; ++r) {
        int m = m0 + wm + i * 16 + fq * 4 + r;
        out[(size_t)m * OO + o] = tot[i][j][r] + bias;
      }
    }
  }

  if (blockIdx.x == 0 && blockIdx.y == 0 && tid == 0)
    out[(size_t)NROWS * OO] = loss_acc[0];
}

extern "C" void kernel_launch(void* const* d_in, const int* in_sizes, int n_in,
                              void* d_out, int out_size, void* d_ws, size_t ws_size,
                              hipStream_t stream) {
  const float* x     = (const float*)d_in[0];
  // d_in[1] = key_feat (ignored by forward)
  const float* map_w = (const float*)d_in[2];
  const float* map_b = (const float*)d_in[3];
  const float* cent  = (const float*)d_in[4];
  const float* prior = (const float*)d_in[5];
  const float* pw    = (const float*)d_in[6];
  const float* bw    = (const float*)d_in[7];
  const float* bb    = (const float*)d_in[8];
  float* out = (float*)d_out;

  // ws layout
  char* wsp = (char*)d_ws;
  float* resp = (float*)wsp;                                       // 524288 B
  float* loss = (float*)(wsp + 524288);                            // 16 B slot
  unsigned short* xb = (unsigned short*)(wsp + 524304);            // 16777216 B
  unsigned short* wb = (unsigned short*)(wsp + 524304 + 16777216); // 4718592 B
  float* wT4 = (float*)(wsp + 524304 + 16777216 + 4718592);        // 131072 B

  hipMemsetAsync(loss, 0, sizeof(float), stream);
  k_prep<<<dim3(NB4 + TB), dim3(256), 0, stream>>>(x, pw, bw, map_w, xb, wb, wT4);
  k_assign<<<dim3(NROWS / 16), dim3(256), 0, stream>>>(x, wT4, map_b, cent, prior, resp, loss);
  dim3 grid(NROWS / 128, OO / 128);
  k_moe<<<grid, dim3(256), 0, stream>>>(xb, wb, bb, resp, loss, out);
}

// Round 4
// 365.968 us; speedup vs baseline: 1.3518x; 1.3518x over previous
//
#include <hip/hip_runtime.h>
#include <hip/hip_bf16.h>

// Problem constants (T=2048, B=8, C=512, O=512, RD=64, NE=8, tau=1, commit=0.1)
// All I/O float32. Single fused GEMM over K'=9*512: resp folded into A at
// staging (bf16), B = [pw_w;bias_w] bf16 via global_load_lds. Single 64-reg
// accumulator (round-3 spill fix: WRITE_SIZE 352MB was dual-acc scratch).
#define NROWS 16384
#define CC 512
#define OO 512
#define RDIM 64
#define NE 8
#define NEXP 9            // 8 experts + bias_w as expert 8 (scale 1.0)
#define COMMIT_SCALE 0.1f
#define LOG2PI_TERM 58.81206612509905f   // (RD/2)*log(2*pi*tau), tau=1

typedef __attribute__((ext_vector_type(8))) short short8;
typedef __attribute__((ext_vector_type(4))) float f32x4;

__device__ __forceinline__ unsigned short f2bf(float f) {
  unsigned int u = __float_as_uint(f);
  u += 0x7fffu + ((u >> 16) & 1u);   // round-to-nearest-even
  return (unsigned short)(u >> 16);
}
// pack 2 f32 -> 2 bf16 (RNE); low half = a
__device__ __forceinline__ unsigned int pk2(float a, float b) {
  return ((unsigned int)f2bf(a)) | (((unsigned int)f2bf(b)) << 16);
}

__device__ __forceinline__ void gl_lds16(const unsigned short* g, unsigned short* l) {
  __builtin_amdgcn_global_load_lds(
      (const __attribute__((address_space(1))) void*)g,
      (__attribute__((address_space(3))) void*)l, 16, 0, 0);
}

// ---------------------------------------------------------------------------
// Kernel 0: f32->bf16 copy of [pw_w ; bias_w] -> wb; transpose map_w -> wT4.
// (x is no longer pre-converted: k_moe stages it f32->bf16 with resp fused.)
// ---------------------------------------------------------------------------
#define P4 524288u    // pw_w float4 count   (2097152 / 4)
#define B4 65536u     // bias_w float4 count (262144 / 4)
#define NCV ((P4 + B4) / 256u)        // 2304 convert blocks
#define TB 128u                        // 32768 map_w elems / 256

__global__ __launch_bounds__(256) void k_prep(
    const float* __restrict__ pw, const float* __restrict__ bw,
    const float* __restrict__ mw,
    unsigned short* __restrict__ wb, float* __restrict__ wT4)
{
  unsigned int b = blockIdx.x;
  if (b >= NCV) {   // map_w transpose: i indexes map_w[j*512+c]
    unsigned int i = (b - NCV) * 256 + threadIdx.x;
    unsigned int j = i >> 9, c = i & 511u;
    wT4[((c >> 2) << 8) + (j << 2) + (c & 3u)] = mw[i];
    return;
  }
  unsigned int i = b * 256 + threadIdx.x;   // float4 index into [pw|bw]
  const float* src = (i < P4) ? (pw + (size_t)i * 4)
                              : (bw + (size_t)(i - P4) * 4);
  unsigned short* dst = wb + (size_t)i * 4;
  float4 v = *(const float4*)src;
  ushort4 o;
  o.x = f2bf(v.x); o.y = f2bf(v.y); o.z = f2bf(v.z); o.w = f2bf(v.w);
  *(ushort4*)dst = o;
}

// ---------------------------------------------------------------------------
// Kernel 1: GMM responsibilities + loss (pure f32).
// One wave = 4 rows; lane j owns k_j. map_w read coalesced via wT4.
// ---------------------------------------------------------------------------
__global__ __launch_bounds__(256) void k_assign(
    const float* __restrict__ x,      // [N, C]
    const float* __restrict__ wT4,    // [C/4, 64, 4] transposed map_w
    const float* __restrict__ map_b,  // [RD]
    const float* __restrict__ cent,   // [NE, RD]
    const float* __restrict__ prior,  // [NE]
    float* __restrict__ resp_out,     // [N, NE] f32 (ws)
    float* __restrict__ loss_acc)     // [1] f32 (ws)
{
  __shared__ float lsum[4];
  const int tid  = threadIdx.x;
  const int wid  = tid >> 6;
  const int lane = tid & 63;
  const int row0 = blockIdx.x * 16 + wid * 4;

  const float* xr0 = x + (size_t)row0 * CC;
  float acc[4] = {0.f, 0.f, 0.f, 0.f};
  #pragma unroll 4
  for (int c0 = 0; c0 < CC; c0 += 4) {
    float4 wv = *(const float4*)&wT4[(c0 << 6) + (lane << 2)];  // coalesced
    #pragma unroll
    for (int r = 0; r < 4; ++r) {
      float4 xv = *(const float4*)(xr0 + r * CC + c0);          // wave-uniform
      acc[r] += xv.x * wv.x + xv.y * wv.y + xv.z * wv.z + xv.w * wv.w;
    }
  }
  const float mb = map_b[lane];
  float kk[4] = {acc[0] + mb, acc[1] + mb, acc[2] + mb, acc[3] + mb};

  float ce[8], c2[8], lp[8];
  #pragma unroll
  for (int e = 0; e < 8; ++e) {
    ce[e] = cent[e * RDIM + lane];
    float v = ce[e] * ce[e];
    #pragma unroll
    for (int off = 32; off; off >>= 1) v += __shfl_xor(v, off, 64);
    c2[e] = v;
    lp[e] = __logf(prior[e]);
  }

  float dsum = 0.f;
  #pragma unroll
  for (int r = 0; r < 4; ++r) {
    float k = kk[r];
    float v[9];
    v[0] = k * k;
    #pragma unroll
    for (int e = 0; e < 8; ++e) v[e + 1] = k * ce[e];
    #pragma unroll
    for (int off = 32; off; off >>= 1) {
      #pragma unroll
      for (int q = 0; q < 9; ++q) v[q] += __shfl_xor(v[q], off, 64);
    }
    float lr[8], mx = -3.4e38f;
    #pragma unroll
    for (int e = 0; e < 8; ++e) {
      float d2 = v[0] + c2[e] - 2.f * v[e + 1];
      lr[e] = -0.5f * d2 - LOG2PI_TERM + lp[e];
      mx = fmaxf(mx, lr[e]);
    }
    float s = 0.f;
    #pragma unroll
    for (int e = 0; e < 8; ++e) s += __expf(lr[e] - mx);
    float denom = mx + __logf(s);
    dsum += denom;
    float myv = 0.f;
    #pragma unroll
    for (int e = 0; e < 8; ++e) {
      float re = __expf(lr[e] - denom);
      myv = (lane == e) ? re : myv;
    }
    if (lane < 8) resp_out[(size_t)(row0 + r) * NE + lane] = myv;
  }
  if (lane == 0) lsum[wid] = dsum;
  __syncthreads();
  if (tid == 0) {
    float t = lsum[0] + lsum[1] + lsum[2] + lsum[3];
    atomicAdd(loss_acc, -COMMIT_SCALE * t);
  }
}

// ---------------------------------------------------------------------------
// Kernel 2: y[m,o] = sum_e sum_k (resp[m,e]*x[m,k]) * W_e[o,k] + bias_b[o].
// Single accumulator; A staged from f32 x with resp fused (ds_write, padded
// stride 40); B via global_load_lds width-16, unpadded + double-XOR swizzle.
// ---------------------------------------------------------------------------
__global__ __launch_bounds__(256, 3) void k_moe(
    const float* __restrict__ x,             // [N, C] f32
    const unsigned short* __restrict__ wb,   // [9, O, C] bf16 (ws)
    const float* __restrict__ bb,            // [O] f32
    const float* __restrict__ resp,          // [N, NE] f32 (ws)
    const float* __restrict__ loss_acc,      // [1] f32 (ws)
    float* __restrict__ out)                 // [N*O + 1] f32
{
  __shared__ unsigned short aT[128 * 40];    // padded, stride 40 shorts
  __shared__ unsigned short bT[128 * 32];    // unpadded (global_load_lds)
  __shared__ float sc[NEXP * 128];

  const int tid = threadIdx.x;
  const int m0 = blockIdx.x * 128;
  const int o0 = blockIdx.y * 128;

  // resp scales: sc[e][row]; expert 8 (bias_w) = 1.0
  for (int idx = tid; idx < 128 * NE; idx += 256) {
    int r = idx >> 3, e = idx & 7;
    sc[e * 128 + r] = resp[(size_t)(m0 + r) * NE + e];
  }
  if (tid < 128) sc[8 * 128 + tid] = 1.0f;
  __syncthreads();

  const int lane = tid & 63;
  const int wid = tid >> 6;
  const int wm = (wid & 1) * 64;
  const int wn = (wid >> 1) * 64;
  const int fr = lane & 15;      // A: m within tile / B: n within tile
  const int fq = lane >> 4;      // k chunk (*8 shorts), C/D row chunk (*4)

  // A staging: thread covers row srow, 16 k at scol.
  const int srow = tid >> 1;
  const int scol = (tid & 1) * 16;
  const float4* xr4 = (const float4*)(x + (size_t)(m0 + srow) * CC + scol);

  // B staging via global_load_lds: lane l -> row l>>2 (16 rows/call), LDS
  // chunk pos l&3, fetches global chunk (l&3)^swz(row); swz(r)=(r&3)^((r>>2)&3).
  const int srB = lane >> 2;
  const int gchunk = (lane & 3) ^ (srB & 3) ^ ((srB >> 2) & 3);
  const size_t b_go = (size_t)(o0 + wid * 32 + srB) * CC + gchunk * 8;
  unsigned short* b_l0 = bT + wid * 1024;
  unsigned short* b_l1 = b_l0 + 512;
  const size_t row16 = (size_t)16 * CC;
  const int rchunkB = (fq ^ (fr & 3) ^ ((fr >> 2) & 3)) * 8;

  f32x4 zero4 = {0.f, 0.f, 0.f, 0.f};
  f32x4 acc[4][4];
  #pragma unroll
  for (int i = 0; i < 4; ++i)
    #pragma unroll
    for (int j = 0; j < 4; ++j) acc[i][j] = zero4;

  for (int e = 0; e < NEXP; ++e) {
    const unsigned short* Bb = wb + (size_t)e * OO * CC + b_go;
    const float s = sc[e * 128 + srow];

    #pragma unroll 2
    for (int kk = 0; kk < 16; ++kk) {
      __syncthreads();   // previous tile's readers done
      gl_lds16(Bb + kk * 32,         b_l0);
      gl_lds16(Bb + kk * 32 + row16, b_l1);
      // A: 16 f32 -> scale -> bf16 -> LDS
      float4 v0 = xr4[kk * 8 + 0], v1 = xr4[kk * 8 + 1];
      float4 v2 = xr4[kk * 8 + 2], v3 = xr4[kk * 8 + 3];
      uint4 w0, w1;
      w0.x = pk2(v0.x * s, v0.y * s); w0.y = pk2(v0.z * s, v0.w * s);
      w0.z = pk2(v1.x * s, v1.y * s); w0.w = pk2(v1.z * s, v1.w * s);
      w1.x = pk2(v2.x * s, v2.y * s); w1.y = pk2(v2.z * s, v2.w * s);
      w1.z = pk2(v3.x * s, v3.y * s); w1.w = pk2(v3.z * s, v3.w * s);
      *(uint4*)&aT[srow * 40 + scol]     = w0;
      *(uint4*)&aT[srow * 40 + scol + 8] = w1;
      __syncthreads();   // vmcnt+lgkmcnt drain

      short8 af[4], bfr[4];
      #pragma unroll
      for (int i = 0; i < 4; ++i)
        af[i] = *(const short8*)&aT[(wm + i * 16 + fr) * 40 + fq * 8];
      #pragma unroll
      for (int j = 0; j < 4; ++j)
        bfr[j] = *(const short8*)&bT[(wn + j * 16 + fr) * 32 + rchunkB];

      #pragma unroll
      for (int i = 0; i < 4; ++i)
        #pragma unroll
        for (int j = 0; j < 4; ++j)
          acc[i][j] = __builtin_amdgcn_mfma_f32_16x16x32_bf16(af[i], bfr[j], acc[i][j], 0, 0, 0);
    }
  }

  // epilogue: + bias_b, store f32
  #pragma unroll
  for (int j = 0; j < 4; ++j) {
    const int o = o0 + wn + j * 16 + fr;
    const float bias = bb[o];
    #pragma unroll
    for (int i = 0; i < 4; ++i) {
      #pragma unroll
      for (int r = 0; r < 4; ++r) {
        int m = m0 + wm + i * 16 + fq * 4 + r;
        out[(size_t)m * OO + o] = acc[i][j][r] + bias;
      }
    }
  }

  if (blockIdx.x == 0 && blockIdx.y == 0 && tid == 0)
    out[(size_t)NROWS * OO] = loss_acc[0];
}

extern "C" void kernel_launch(void* const* d_in, const int* in_sizes, int n_in,
                              void* d_out, int out_size, void* d_ws, size_t ws_size,
                              hipStream_t stream) {
  const float* x     = (const float*)d_in[0];
  // d_in[1] = key_feat (ignored by forward)
  const float* map_w = (const float*)d_in[2];
  const float* map_b = (const float*)d_in[3];
  const float* cent  = (const float*)d_in[4];
  const float* prior = (const float*)d_in[5];
  const float* pw    = (const float*)d_in[6];
  const float* bw    = (const float*)d_in[7];
  const float* bb    = (const float*)d_in[8];
  float* out = (float*)d_out;

  // ws layout
  char* wsp = (char*)d_ws;
  float* resp = (float*)wsp;                              // 524288 B
  float* loss = (float*)(wsp + 524288);                   // 16 B slot
  unsigned short* wb = (unsigned short*)(wsp + 524304);   // 4718592 B
  float* wT4 = (float*)(wsp + 524304 + 4718592);          // 131072 B

  hipMemsetAsync(loss, 0, sizeof(float), stream);
  k_prep<<<dim3(NCV + TB), dim3(256), 0, stream>>>(pw, bw, map_w, wb, wT4);
  k_assign<<<dim3(NROWS / 16), dim3(256), 0, stream>>>(x, wT4, map_b, cent, prior, resp, loss);
  dim3 grid(NROWS / 128, OO / 128);
  k_moe<<<grid, dim3(256), 0, stream>>>(x, wb, bb, resp, loss, out);
}